// Round 20
// baseline (71.578 us; speedup 1.0000x reference)
//
#include <hip/hip_runtime.h>
#include <math.h>

#define D        256
#define KNN      8
#define G        16           // grid cells per axis
#define NCELL    (G*G*G)
#define CS       0.625f       // cell size = 10/16, exactly representable
#define EPS_D2   2e-3f        // margin >> f32 rounding error of reference d2
#define CAP      64           // fixed bin capacity (Poisson(12.2); P(>64)~1e-40)
#define SPILLMAX 50000        // spill can hold every point -> never drops

typedef unsigned long long u64;
typedef __attribute__((ext_vector_type(8))) short bf16x8;   // 8 bf16 = 4 VGPRs
typedef __attribute__((ext_vector_type(4))) float f32x4;

// f32 -> bf16 round-to-nearest-even
__device__ __forceinline__ unsigned short f2b(float f) {
    unsigned u = __float_as_uint(f);
    u += 0x7fff + ((u >> 16) & 1);
    return (unsigned short)(u >> 16);
}
__device__ __forceinline__ bf16x8 pack8(float4 a, float4 b) {
    bf16x8 r;
    r[0] = (short)f2b(a.x); r[1] = (short)f2b(a.y);
    r[2] = (short)f2b(a.z); r[3] = (short)f2b(a.w);
    r[4] = (short)f2b(b.x); r[5] = (short)f2b(b.y);
    r[6] = (short)f2b(b.z); r[7] = (short)f2b(b.w);
    return r;
}

// orderable-float transform: monotonic u32 for any f32 (handles negatives)
__device__ __forceinline__ unsigned enc_f32(float f) {
    unsigned b = __float_as_uint(f);
    return b ^ ((unsigned)(((int)b) >> 31) | 0x80000000u);
}
__device__ __forceinline__ float dec_f32(unsigned t) {
    unsigned m = (unsigned)(((int)t) >> 31);
    return __uint_as_float(t ^ (0x80000000u | ~m));
}
__device__ __forceinline__ u64 mkkey(float d2, int j) {
    return ((u64)enc_f32(d2) << 32) | (u64)(unsigned)j;
}
__device__ __forceinline__ int cell_of(float x) {
    int c = (int)(x * 1.6f);
    return c < 0 ? 0 : (c > G-1 ? G-1 : c);
}

#define INSERT8(xk)                                                            \
    if ((xk) < k7) {                                                           \
        const bool c0 = (xk) < k0, c1 = (xk) < k1, c2 = (xk) < k2,             \
                   c3 = (xk) < k3, c4 = (xk) < k4, c5 = (xk) < k5,             \
                   c6 = (xk) < k6;                                             \
        k7 = c6 ? k6 : (xk);                                                   \
        k6 = c5 ? k5 : (c6 ? (xk) : k6);                                       \
        k5 = c4 ? k4 : (c5 ? (xk) : k5);                                       \
        k4 = c3 ? k3 : (c4 ? (xk) : k4);                                       \
        k3 = c2 ? k2 : (c3 ? (xk) : k3);                                       \
        k2 = c1 ? k1 : (c2 ? (xk) : k2);                                       \
        k1 = c0 ? k0 : (c1 ? (xk) : k1);                                       \
        k0 = c0 ? (xk) : k0;                                                   \
    }

// bit-exact np/BLAS f32 d2: dot = fma(qz,pz, fma(qy,py, fl(qx*px)));
//                           d2  = (sq - fl(2*dot)) + sp
#define SCORE(p)                                                               \
    {                                                                          \
        const float sp  = __fadd_rn(__fadd_rn(__fmul_rn((p).x,(p).x),          \
                                  __fmul_rn((p).y,(p).y)), __fmul_rn((p).z,(p).z)); \
        const float dot = __fmaf_rn(qz,(p).z, __fmaf_rn(qy,(p).y, __fmul_rn(qx,(p).x))); \
        const float d2  = __fadd_rn(__fsub_rn(sq, __fmul_rn(2.0f, dot)), sp);  \
        const u64 xk = mkkey(d2, __float_as_int((p).w));                       \
        INSERT8(xk)                                                            \
    }

__device__ __forceinline__ void wave_merge8(int l, u64& k0, u64& k1, u64& k2, u64& k3,
                                            u64& k4, u64& k5, u64& k6, u64& k7,
                                            u64& mine)
{
#pragma unroll
    for (int rd = 0; rd < KNN; ++rd) {
        u64 m = k0;
#pragma unroll
        for (int o = 32; o; o >>= 1) {
            const u64 t = __shfl_xor(m, o);
            if (t < m) m = t;
        }
        if (k0 == m) {   // owner pops its sorted list
            k0 = k1; k1 = k2; k2 = k3; k3 = k4; k4 = k5; k5 = k6; k6 = k7;
            k7 = ~0ull;
        }
        if (l == rd) mine = m;
    }
}

// ---------------------------------------------------------------------------
// Prep (r16-proven): blocks 0..7 -> wk2 = w_k @ w_q; blocks 8..11 -> zero
// counters; blocks 12..107 -> convert w_q/w_v/w_o to bf16 (RNE).
// ---------------------------------------------------------------------------
__global__ __launch_bounds__(256) void prep(const float* __restrict__ w_k,
                                            const float* __restrict__ w_q,
                                            const float* __restrict__ w_v,
                                            const float* __restrict__ w_o,
                                            float* __restrict__ wk2,
                                            unsigned short* __restrict__ wqb,
                                            unsigned short* __restrict__ wvb,
                                            unsigned short* __restrict__ wob,
                                            int4* __restrict__ cnt4,
                                            int* __restrict__ spill_cnt)
{
    const int b = blockIdx.x, t = threadIdx.x;
    if (b < 8) {
        float acc = 0.f;
#pragma unroll 8
        for (int d = 0; d < D; ++d)
            acc = fmaf(w_k[b*D + d], w_q[(size_t)d*D + t], acc);
        wk2[b*D + t] = acc;
    } else if (b < 12) {
        cnt4[(b-8)*256 + t] = make_int4(0, 0, 0, 0);
        if (b == 8 && t == 0) *spill_cnt = 0;
    } else {
        const int m = (b - 12) >> 5;                 // 0,1,2 -> wq,wv,wo
        const int local = (b - 12) & 31;
        const size_t e = (size_t)local * 2048 + (size_t)t * 8;
        const float* src = (m == 0) ? w_q : (m == 1) ? w_v : w_o;
        unsigned short* dst = (m == 0) ? wqb : (m == 1) ? wvb : wob;
        const float4 x0 = *(const float4*)&src[e];
        const float4 x1 = *(const float4*)&src[e + 4];
        *(bf16x8*)&dst[e] = pack8(x0, x1);
    }
}

__global__ __launch_bounds__(256) void scatter_bins(const float* __restrict__ spc,
                                                    int* __restrict__ cnt,
                                                    float4* __restrict__ bins,
                                                    int* __restrict__ spill_cnt,
                                                    float4* __restrict__ spill, int N)
{
    const int j = blockIdx.x * 256 + threadIdx.x;
    if (j >= N) return;
    const float px = spc[3*j+0], py = spc[3*j+1], pz = spc[3*j+2];
    const int cell = cell_of(px) | (cell_of(py) << 4) | (cell_of(pz) << 8);
    const float4 p = make_float4(px, py, pz, __int_as_float(j));
    const int pos = atomicAdd(&cnt[cell], 1);
    if (pos < CAP) bins[cell*CAP + pos] = p;
    else {
        const int sp = atomicAdd(spill_cnt, 1);
        if (sp < SPILLMAX) spill[sp] = p;
    }
}

// ---------------------------------------------------------------------------
// mega5: 512 blocks x 1024 threads (16 waves), 4 queries/block, 4 waves per
// query in Phase A -> 8192 waves total (vs 2048): latency hiding at last.
// Phase A: wave part p of query qi scans 16 cells (4 lanes/cell, points
//   strided 4), per-wave top-8 -> cand LDS -> part-0 wave merges 32 cands
//   (r13-verified two-level merge), stop test + exact fallback, gate softmax,
//   gather, writes tiles.
// Phase B: 16 waves x 1 n-tile (16 cols each), verified MFMA layouts,
//   residual + LN.
// ---------------------------------------------------------------------------
__global__ __launch_bounds__(1024, 4) void mega5(const float* __restrict__ qpos,
                                                 const float4* __restrict__ bins,
                                                 const int* __restrict__ cnt,
                                                 const int* __restrict__ spill_cnt,
                                                 const float4* __restrict__ spill,
                                                 const float* __restrict__ query,
                                                 const float* __restrict__ wk2,
                                                 const float* __restrict__ w_b,
                                                 const float* __restrict__ feats,
                                                 const unsigned short* __restrict__ wqb,
                                                 const unsigned short* __restrict__ wvb,
                                                 const unsigned short* __restrict__ wob,
                                                 const float* __restrict__ gmm,
                                                 const float* __restrict__ bta,
                                                 float* __restrict__ out)
{
    __shared__ unsigned short a_lds[16][264];   // query bf16 (rows 4-15 zero)
    __shared__ unsigned short f_lds[16][264];   // fbar  bf16 (rows 4-15 zero)
    __shared__ unsigned short w_lds[16][264];   // q*v   bf16
    __shared__ float q_f32[4][260];             // query f32 (residual)
    __shared__ float o_f32[4][260];             // out_pre f32 (LN)
    __shared__ u64  cand[4][32];                // per-query 4x8 candidates

    const int tid = threadIdx.x;
    const int wv  = tid >> 6, l = tid & 63;
    const int qi  = wv >> 2, part = wv & 3;     // query-in-block, wave part
    const int r0  = blockIdx.x * 4;
    const int q   = r0 + qi;

    // zero pad rows 4..15 of a_lds/f_lds: 768 octets spread over 1024 thr
    if (tid < 768) {
        const int oo = (tid < 384) ? tid : tid - 384;
        const int row = 4 + (oo >> 5);
        const int c8 = (oo & 31) * 8;
        const bf16x8 z = {0,0,0,0,0,0,0,0};
        if (tid < 384) *(bf16x8*)&a_lds[row][c8] = z;
        else           *(bf16x8*)&f_lds[row][c8] = z;
    }

    // ================= Phase A1: quarter-scan (all 16 waves) =================
    const float qx = qpos[3*q+0], qy = qpos[3*q+1], qz = qpos[3*q+2];
    const float sq = __fadd_rn(__fadd_rn(__fmul_rn(qx,qx), __fmul_rn(qy,qy)),
                               __fmul_rn(qz,qz));
    const int cx = cell_of(qx), cy = cell_of(qy), cz = cell_of(qz);

    auto bstart = [](int c, float coord) {
        const float f = coord * 1.6f - (float)c;
        int b = c + ((f < 0.5f) ? -2 : -1);
        return b < 0 ? 0 : (b > G-4 ? G-4 : b);
    };
    const int bx = bstart(cx, qx), by = bstart(cy, qy), bz = bstart(cz, qz);

    u64 k0 = ~0ull, k1 = ~0ull, k2 = ~0ull, k3 = ~0ull,
        k4 = ~0ull, k5 = ~0ull, k6 = ~0ull, k7 = ~0ull;

    {   // cell c = part*16 + (l>>2); 4 lanes/cell, points strided 4
        const int c = part*16 + (l >> 2), sub = l & 3;
        const int x = bx + (c & 3), y = by + ((c >> 2) & 3), z = bz + (c >> 4);
        const int ci = x | (y << 4) | (z << 8);
        const int n = min(cnt[ci], CAP);
        const int st = ci * CAP;
        for (int i = sub; i < n; i += 4) { const float4 p = bins[st + i]; SCORE(p) }
    }
    if (part == 0) {   // spill list scanned once per query (normally empty)
        const int ns = min(*spill_cnt, SPILLMAX);
        for (int i = l; i < ns; i += 64) { const float4 p = spill[i]; SCORE(p) }
    }

    u64 mine = ~0ull;
    wave_merge8(l, k0, k1, k2, k3, k4, k5, k6, k7, mine);
    if (l < KNN) cand[qi][part*KNN + l] = mine;
    __syncthreads();

    // ================= Phase A2: final merge + gate + gather (part 0) =======
    if (part == 0) {
        u64 k = (l < 32) ? cand[qi][l] : ~0ull;
        u64 m2 = ~0ull;
#pragma unroll
        for (int rd = 0; rd < KNN; ++rd) {
            u64 m = k;
#pragma unroll
            for (int o = 32; o; o >>= 1) {
                const u64 t = __shfl_xor(m, o);
                if (t < m) m = t;
            }
            if (k == m) k = ~0ull;
            if (l == rd) m2 = m;
        }
        const u64 worst = __shfl(m2, KNN-1);
        const float w8 = dec_f32((unsigned)(worst >> 32));   // NaN if <8 cands
        float dmin = INFINITY;
        if (bx > 0)     dmin = fminf(dmin, qx - (float)bx * CS);
        if (bx + 4 < G) dmin = fminf(dmin, (float)(bx + 4) * CS - qx);
        if (by > 0)     dmin = fminf(dmin, qy - (float)by * CS);
        if (by + 4 < G) dmin = fminf(dmin, (float)(by + 4) * CS - qy);
        if (bz > 0)     dmin = fminf(dmin, qz - (float)bz * CS);
        if (bz + 4 < G) dmin = fminf(dmin, (float)(bz + 4) * CS - qz);

        if (!(w8 + EPS_D2 <= dmin * dmin)) {
            // exact fallback (prob ~0): keep merged top-8, scan all cells
            // outside the block (spill already merged in)
            k0 = (l < KNN) ? m2 : ~0ull;
            k1 = ~0ull; k2 = ~0ull; k3 = ~0ull; k4 = ~0ull;
            k5 = ~0ull; k6 = ~0ull; k7 = ~0ull;
            for (int c = l; c < NCELL; c += 64) {
                const int x = c & 15, y = (c >> 4) & 15, z = c >> 8;
                if (x >= bx && x < bx+4 && y >= by && y < by+4 && z >= bz && z < bz+4) continue;
                const int n = min(cnt[c], CAP);
                const int st = c * CAP;
                for (int i = 0; i < n; ++i) { const float4 p = bins[st + i]; SCORE(p) }
            }
            wave_merge8(l, k0, k1, k2, k3, k4, k5, k6, k7, m2);
        }

        // ids broadcast from lanes 0..7
        int ids[KNN];
        const int my_id = (int)(unsigned)(m2 & 0xffffffffu);
#pragma unroll
        for (int j = 0; j < KNN; ++j) ids[j] = __shfl(my_id, j);

        // gate = softmax(query[q] @ wk2^T + w_b)
        const float4 qv = *(const float4*)&query[(size_t)q*D + l*4];
        float logit[KNN];
#pragma unroll
        for (int j = 0; j < KNN; ++j) {
            const float4 w = *(const float4*)&wk2[(size_t)j*D + l*4];
            logit[j] = fmaf(qv.x, w.x, fmaf(qv.y, w.y, fmaf(qv.z, w.z, qv.w*w.w)));
        }
#pragma unroll
        for (int o = 32; o; o >>= 1) {
#pragma unroll
            for (int j = 0; j < KNN; ++j) logit[j] += __shfl_xor(logit[j], o);
        }
#pragma unroll
        for (int j = 0; j < KNN; ++j) logit[j] += w_b[j];

        float m = logit[0];
#pragma unroll
        for (int j = 1; j < KNN; ++j) m = fmaxf(m, logit[j]);
        float e[KNN]; float ssum = 0.f;
#pragma unroll
        for (int j = 0; j < KNN; ++j) { e[j] = expf(logit[j] - m); ssum += e[j]; }
        const float inv = 1.f / ssum;

        float4 acc4 = make_float4(0.f, 0.f, 0.f, 0.f);
#pragma unroll
        for (int j = 0; j < KNN; ++j) {
            const float gj = e[j] * inv;
            const float4 f = *(const float4*)&feats[(size_t)ids[j]*D + l*4];
            acc4.x = fmaf(gj, f.x, acc4.x);
            acc4.y = fmaf(gj, f.y, acc4.y);
            acc4.z = fmaf(gj, f.z, acc4.z);
            acc4.w = fmaf(gj, f.w, acc4.w);
        }

        // write tiles: q (f32 + bf16) and fbar (bf16), row qi
        *(float4*)&q_f32[qi][l*4] = qv;
        short4 qb; qb.x = (short)f2b(qv.x); qb.y = (short)f2b(qv.y);
                   qb.z = (short)f2b(qv.z); qb.w = (short)f2b(qv.w);
        *(short4*)&a_lds[qi][l*4] = qb;
        short4 fv; fv.x = (short)f2b(acc4.x); fv.y = (short)f2b(acc4.y);
                   fv.z = (short)f2b(acc4.z); fv.w = (short)f2b(acc4.w);
        *(short4*)&f_lds[qi][l*4] = fv;
    }
    __syncthreads();

    // ================= Phase B: MFMA chain, wave wv -> cols [16wv,16wv+16) ==
    const int mrow = l & 15;
    const int kq   = (l >> 4) * 8;
    const int ncol = wv*16 + mrow;

    f32x4 aq = (f32x4){0.f, 0.f, 0.f, 0.f};
    f32x4 av = (f32x4){0.f, 0.f, 0.f, 0.f};
#pragma unroll
    for (int k0i = 0; k0i < D; k0i += 32) {
        const bf16x8 af = *(const bf16x8*)&a_lds[mrow][k0i + kq];
        const bf16x8 ff = *(const bf16x8*)&f_lds[mrow][k0i + kq];
        const bf16x8 bq = *(const bf16x8*)&wqb[(size_t)ncol*D + k0i + kq];
        const bf16x8 bv = *(const bf16x8*)&wvb[(size_t)ncol*D + k0i + kq];
        aq = __builtin_amdgcn_mfma_f32_16x16x32_bf16(af, bq, aq, 0, 0, 0);
        av = __builtin_amdgcn_mfma_f32_16x16x32_bf16(ff, bv, av, 0, 0, 0);
    }
#pragma unroll
    for (int r = 0; r < 4; ++r) {
        const int row = (l >> 4) * 4 + r;
        const int col = wv*16 + (l & 15);
        w_lds[row][col] = f2b(aq[r] * av[r]);
    }
    __syncthreads();

    f32x4 ao = (f32x4){0.f, 0.f, 0.f, 0.f};
#pragma unroll
    for (int k0i = 0; k0i < D; k0i += 32) {
        const bf16x8 wf = *(const bf16x8*)&w_lds[mrow][k0i + kq];
        const bf16x8 bo = *(const bf16x8*)&wob[(size_t)ncol*D + k0i + kq];
        ao = __builtin_amdgcn_mfma_f32_16x16x32_bf16(wf, bo, ao, 0, 0, 0);
    }
#pragma unroll
    for (int r = 0; r < 4; ++r) {
        const int row = (l >> 4) * 4 + r;
        if (row < 4) {
            const int col = wv*16 + (l & 15);
            o_f32[row][col] = ao[r] + q_f32[row][col];
        }
    }
    __syncthreads();

    // ---- LayerNorm: waves 0..3 -> rows 0..3 ----
    if (wv < 4) {
        const float4 v = *(const float4*)&o_f32[wv][l*4];
        float s  = (v.x + v.y) + (v.z + v.w);
        float s2 = fmaf(v.x, v.x, fmaf(v.y, v.y, fmaf(v.z, v.z, v.w*v.w)));
#pragma unroll
        for (int o = 32; o; o >>= 1) { s += __shfl_xor(s, o); s2 += __shfl_xor(s2, o); }
        const float mu  = s * (1.f/256.f);
        const float var = fmaf(s2, 1.f/256.f, -mu*mu);
        const float rs  = rsqrtf(var + 1e-5f);
        const float4 g = *(const float4*)&gmm[l*4];
        const float4 b = *(const float4*)&bta[l*4];
        float4 o4;
        o4.x = (v.x - mu) * rs * g.x + b.x;
        o4.y = (v.y - mu) * rs * g.y + b.y;
        o4.z = (v.z - mu) * rs * g.z + b.z;
        o4.w = (v.w - mu) * rs * g.w + b.w;
        *(float4*)&out[(size_t)(r0+wv)*D + l*4] = o4;
    }
}

// ---------------------------------------------------------------------------
extern "C" void kernel_launch(void* const* d_in, const int* in_sizes, int n_in,
                              void* d_out, int out_size, void* d_ws, size_t ws_size,
                              hipStream_t stream)
{
    const float* query = (const float*)d_in[0];
    const float* qpos  = (const float*)d_in[1];
    const float* feats = (const float*)d_in[2];
    const float* spc   = (const float*)d_in[3];
    const float* w_q   = (const float*)d_in[4];
    const float* w_v   = (const float*)d_in[5];
    const float* w_o   = (const float*)d_in[6];
    const float* w_k   = (const float*)d_in[7];
    const float* w_b   = (const float*)d_in[8];
    const float* gamma = (const float*)d_in[9];
    const float* beta  = (const float*)d_in[10];

    const int Nq = in_sizes[0] / D;   // 2048
    const int N  = in_sizes[2] / D;   // 50000

    char* ws = (char*)d_ws;
    size_t off = 0;
    int* cnt = (int*)(ws + off);               off += ((size_t)NCELL * 4 + 255) & ~(size_t)255;
    int* spill_cnt = (int*)(ws + off);         off += 256;
    float* wk2 = (float*)(ws + off);           off += ((size_t)KNN * D * 4 + 255) & ~(size_t)255;
    unsigned short* wqb = (unsigned short*)(ws + off); off += (size_t)D * D * 2;
    unsigned short* wvb = (unsigned short*)(ws + off); off += (size_t)D * D * 2;
    unsigned short* wob = (unsigned short*)(ws + off); off += (size_t)D * D * 2;
    float4* bins = (float4*)(ws + off);        off += ((size_t)NCELL * CAP * 16 + 255) & ~(size_t)255;
    float4* spill = (float4*)(ws + off);       off += ((size_t)SPILLMAX * 16 + 255) & ~(size_t)255;

    prep<<<108, 256, 0, stream>>>(w_k, w_q, w_v, w_o, wk2, wqb, wvb, wob,
                                  (int4*)cnt, spill_cnt);
    scatter_bins<<<(N + 255)/256, 256, 0, stream>>>(spc, cnt, bins, spill_cnt, spill, N);
    mega5<<<Nq/4, 1024, 0, stream>>>(qpos, bins, cnt, spill_cnt, spill,
                                     query, wk2, w_b, feats, wqb, wvb, wob,
                                     gamma, beta, (float*)d_out);
}

// Round 21
// 45.441 us; speedup vs baseline: 1.5752x; 1.5752x over previous
//
#include <hip/hip_runtime.h>
#include <math.h>

#define D        256
#define KNN      8
#define G        16           // grid cells per axis
#define NCELL    (G*G*G)
#define CS       0.625f       // cell size = 10/16, exactly representable
#define EPS_D2   2e-3f        // margin >> f32 rounding error of reference d2
#define CAP      64           // fixed bin capacity (Poisson(12.2); P(>64)~1e-40)
#define SPILLMAX 50000        // spill can hold every point -> never drops

typedef unsigned long long u64;
typedef __attribute__((ext_vector_type(8))) short bf16x8;   // 8 bf16 = 4 VGPRs
typedef __attribute__((ext_vector_type(4))) float f32x4;

// f32 -> bf16 round-to-nearest-even
__device__ __forceinline__ unsigned short f2b(float f) {
    unsigned u = __float_as_uint(f);
    u += 0x7fff + ((u >> 16) & 1);
    return (unsigned short)(u >> 16);
}
__device__ __forceinline__ bf16x8 pack8(float4 a, float4 b) {
    bf16x8 r;
    r[0] = (short)f2b(a.x); r[1] = (short)f2b(a.y);
    r[2] = (short)f2b(a.z); r[3] = (short)f2b(a.w);
    r[4] = (short)f2b(b.x); r[5] = (short)f2b(b.y);
    r[6] = (short)f2b(b.z); r[7] = (short)f2b(b.w);
    return r;
}

// orderable-float transform: monotonic u32 for any f32 (handles negatives)
__device__ __forceinline__ unsigned enc_f32(float f) {
    unsigned b = __float_as_uint(f);
    return b ^ ((unsigned)(((int)b) >> 31) | 0x80000000u);
}
__device__ __forceinline__ float dec_f32(unsigned t) {
    unsigned m = (unsigned)(((int)t) >> 31);
    return __uint_as_float(t ^ (0x80000000u | ~m));
}
__device__ __forceinline__ u64 mkkey(float d2, int j) {
    return ((u64)enc_f32(d2) << 32) | (u64)(unsigned)j;
}
__device__ __forceinline__ int cell_of(float x) {
    int c = (int)(x * 1.6f);
    return c < 0 ? 0 : (c > G-1 ? G-1 : c);
}

#define INSERT8(xk)                                                            \
    if ((xk) < k7) {                                                           \
        const bool c0 = (xk) < k0, c1 = (xk) < k1, c2 = (xk) < k2,             \
                   c3 = (xk) < k3, c4 = (xk) < k4, c5 = (xk) < k5,             \
                   c6 = (xk) < k6;                                             \
        k7 = c6 ? k6 : (xk);                                                   \
        k6 = c5 ? k5 : (c6 ? (xk) : k6);                                       \
        k5 = c4 ? k4 : (c5 ? (xk) : k5);                                       \
        k4 = c3 ? k3 : (c4 ? (xk) : k4);                                       \
        k3 = c2 ? k2 : (c3 ? (xk) : k3);                                       \
        k2 = c1 ? k1 : (c2 ? (xk) : k2);                                       \
        k1 = c0 ? k0 : (c1 ? (xk) : k1);                                       \
        k0 = c0 ? (xk) : k0;                                                   \
    }

// bit-exact np/BLAS f32 d2: dot = fma(qz,pz, fma(qy,py, fl(qx*px)));
//                           d2  = (sq - fl(2*dot)) + sp
#define SCORE(p)                                                               \
    {                                                                          \
        const float sp  = __fadd_rn(__fadd_rn(__fmul_rn((p).x,(p).x),          \
                                  __fmul_rn((p).y,(p).y)), __fmul_rn((p).z,(p).z)); \
        const float dot = __fmaf_rn(qz,(p).z, __fmaf_rn(qy,(p).y, __fmul_rn(qx,(p).x))); \
        const float d2  = __fadd_rn(__fsub_rn(sq, __fmul_rn(2.0f, dot)), sp);  \
        const u64 xk = mkkey(d2, __float_as_int((p).w));                       \
        INSERT8(xk)                                                            \
    }

__device__ __forceinline__ void wave_merge8(int l, u64& k0, u64& k1, u64& k2, u64& k3,
                                            u64& k4, u64& k5, u64& k6, u64& k7,
                                            u64& mine)
{
#pragma unroll
    for (int rd = 0; rd < KNN; ++rd) {
        u64 m = k0;
#pragma unroll
        for (int o = 32; o; o >>= 1) {
            const u64 t = __shfl_xor(m, o);
            if (t < m) m = t;
        }
        if (k0 == m) {   // owner pops its sorted list
            k0 = k1; k1 = k2; k2 = k3; k3 = k4; k4 = k5; k5 = k6; k6 = k7;
            k7 = ~0ull;
        }
        if (l == rd) mine = m;
    }
}

// ---------------------------------------------------------------------------
// Prep: blocks 0..7  -> wk2 = w_k @ w_q; blocks 8..11 -> zero counters;
// blocks 12..107 -> convert w_q/w_v/w_o to bf16 in MFMA-FRAGMENT-SWIZZLED
// order: octet index idx = (nt*8 + ks)*64 + l  holds cols nt*16+(l&15),
// k = ks*32+(l>>4)*8. A wave's B-frag load is then base + l*16B: COALESCED.
// Same f2b of same elements -> fragment values bit-identical to r16.
// ---------------------------------------------------------------------------
__global__ __launch_bounds__(256) void prep(const float* __restrict__ w_k,
                                            const float* __restrict__ w_q,
                                            const float* __restrict__ w_v,
                                            const float* __restrict__ w_o,
                                            float* __restrict__ wk2,
                                            unsigned short* __restrict__ wqs,
                                            unsigned short* __restrict__ wvs,
                                            unsigned short* __restrict__ wos,
                                            int4* __restrict__ cnt4,
                                            int* __restrict__ spill_cnt)
{
    const int b = blockIdx.x, t = threadIdx.x;
    if (b < 8) {
        float acc = 0.f;
#pragma unroll 8
        for (int d = 0; d < D; ++d)
            acc = fmaf(w_k[b*D + d], w_q[(size_t)d*D + t], acc);
        wk2[b*D + t] = acc;
    } else if (b < 12) {
        cnt4[(b-8)*256 + t] = make_int4(0, 0, 0, 0);
        if (b == 8 && t == 0) *spill_cnt = 0;
    } else {
        const int m = (b - 12) >> 5;                 // 0,1,2 -> wq,wv,wo
        const int local = (b - 12) & 31;
        const int idx = local * 256 + t;             // 0..8191 octets
        const int nt = idx >> 9;                     // n-tile 0..15
        const int ks = (idx >> 6) & 7;               // k-step 0..7
        const int l  = idx & 63;                     // lane
        const int col = nt*16 + (l & 15);
        const int k   = ks*32 + (l >> 4)*8;
        const float* src = (m == 0) ? w_q : (m == 1) ? w_v : w_o;
        unsigned short* dst = (m == 0) ? wqs : (m == 1) ? wvs : wos;
        const float4 x0 = *(const float4*)&src[(size_t)col*D + k];
        const float4 x1 = *(const float4*)&src[(size_t)col*D + k + 4];
        *(bf16x8*)&dst[(size_t)idx * 8] = pack8(x0, x1);
    }
}

__global__ __launch_bounds__(256) void scatter_bins(const float* __restrict__ spc,
                                                    int* __restrict__ cnt,
                                                    float4* __restrict__ bins,
                                                    int* __restrict__ spill_cnt,
                                                    float4* __restrict__ spill, int N)
{
    const int j = blockIdx.x * 256 + threadIdx.x;
    if (j >= N) return;
    const float px = spc[3*j+0], py = spc[3*j+1], pz = spc[3*j+2];
    const int cell = cell_of(px) | (cell_of(py) << 4) | (cell_of(pz) << 8);
    const float4 p = make_float4(px, py, pz, __int_as_float(j));
    const int pos = atomicAdd(&cnt[cell], 1);
    if (pos < CAP) bins[cell*CAP + pos] = p;
    else {
        const int sp = atomicAdd(spill_cnt, 1);
        if (sp < SPILLMAX) spill[sp] = p;
    }
}

// ---------------------------------------------------------------------------
// Per-wave KNN + gate + gather (verified r11/r16/r17 math).
// ---------------------------------------------------------------------------
__device__ __forceinline__ void knn_gate_wave(int q, int l,
                                              const float* __restrict__ qpos,
                                              const float4* __restrict__ bins,
                                              const int* __restrict__ cnt,
                                              const int* __restrict__ spill_cnt,
                                              const float4* __restrict__ spill,
                                              const float* __restrict__ query,
                                              const float* __restrict__ wk2,
                                              const float* __restrict__ w_b,
                                              const float* __restrict__ feats,
                                              float4& qv_out, float4& fb_out)
{
    const float qx = qpos[3*q+0], qy = qpos[3*q+1], qz = qpos[3*q+2];
    const float sq = __fadd_rn(__fadd_rn(__fmul_rn(qx,qx), __fmul_rn(qy,qy)),
                               __fmul_rn(qz,qz));
    const int cx = cell_of(qx), cy = cell_of(qy), cz = cell_of(qz);

    auto bstart = [](int c, float coord) {
        const float f = coord * 1.6f - (float)c;
        int b = c + ((f < 0.5f) ? -2 : -1);
        return b < 0 ? 0 : (b > G-4 ? G-4 : b);
    };
    const int bx = bstart(cx, qx), by = bstart(cy, qy), bz = bstart(cz, qz);

    u64 k0 = ~0ull, k1 = ~0ull, k2 = ~0ull, k3 = ~0ull,
        k4 = ~0ull, k5 = ~0ull, k6 = ~0ull, k7 = ~0ull;

    {   // lane l -> one cell of the 4x4x4 block
        const int x = bx + (l & 3), y = by + ((l >> 2) & 3), z = bz + (l >> 4);
        const int ci = x | (y << 4) | (z << 8);
        const int n = min(cnt[ci], CAP);
        const int st = ci * CAP;
        for (int i = 0; i < n; ++i) { const float4 p = bins[st + i]; SCORE(p) }
    }
    {   // spill list (exactness; normally empty)
        const int ns = min(*spill_cnt, SPILLMAX);
        for (int i = l; i < ns; i += 64) { const float4 p = spill[i]; SCORE(p) }
    }

    u64 mine = ~0ull;
    wave_merge8(l, k0, k1, k2, k3, k4, k5, k6, k7, mine);
    const u64 worst = __shfl(mine, KNN-1);

    const float w8 = dec_f32((unsigned)(worst >> 32));   // NaN if <8 cands
    float dmin = INFINITY;
    if (bx > 0)     dmin = fminf(dmin, qx - (float)bx * CS);
    if (bx + 4 < G) dmin = fminf(dmin, (float)(bx + 4) * CS - qx);
    if (by > 0)     dmin = fminf(dmin, qy - (float)by * CS);
    if (by + 4 < G) dmin = fminf(dmin, (float)(by + 4) * CS - qy);
    if (bz > 0)     dmin = fminf(dmin, qz - (float)bz * CS);
    if (bz + 4 < G) dmin = fminf(dmin, (float)(bz + 4) * CS - qz);

    if (!(w8 + EPS_D2 <= dmin * dmin)) {
        // exact fallback: keep merged top-8, scan every cell outside block
        k0 = (l < KNN) ? mine : ~0ull;
        k1 = ~0ull; k2 = ~0ull; k3 = ~0ull; k4 = ~0ull;
        k5 = ~0ull; k6 = ~0ull; k7 = ~0ull;
        for (int c = l; c < NCELL; c += 64) {
            const int x = c & 15, y = (c >> 4) & 15, z = c >> 8;
            if (x >= bx && x < bx+4 && y >= by && y < by+4 && z >= bz && z < bz+4) continue;
            const int n = min(cnt[c], CAP);
            const int st = c * CAP;
            for (int i = 0; i < n; ++i) { const float4 p = bins[st + i]; SCORE(p) }
        }
        wave_merge8(l, k0, k1, k2, k3, k4, k5, k6, k7, mine);
    }

    // ids broadcast from lanes 0..7
    int ids[KNN];
    const int my_id = (int)(unsigned)(mine & 0xffffffffu);
#pragma unroll
    for (int j = 0; j < KNN; ++j) ids[j] = __shfl(my_id, j);

    // gate = softmax(query[q] @ wk2^T + w_b)
    const float4 qv = *(const float4*)&query[(size_t)q*D + l*4];
    float logit[KNN];
#pragma unroll
    for (int j = 0; j < KNN; ++j) {
        const float4 w = *(const float4*)&wk2[(size_t)j*D + l*4];
        logit[j] = fmaf(qv.x, w.x, fmaf(qv.y, w.y, fmaf(qv.z, w.z, qv.w*w.w)));
    }
#pragma unroll
    for (int o = 32; o; o >>= 1) {
#pragma unroll
        for (int j = 0; j < KNN; ++j) logit[j] += __shfl_xor(logit[j], o);
    }
#pragma unroll
    for (int j = 0; j < KNN; ++j) logit[j] += w_b[j];

    float m = logit[0];
#pragma unroll
    for (int j = 1; j < KNN; ++j) m = fmaxf(m, logit[j]);
    float e[KNN]; float ssum = 0.f;
#pragma unroll
    for (int j = 0; j < KNN; ++j) { e[j] = expf(logit[j] - m); ssum += e[j]; }
    const float inv = 1.f / ssum;

    float4 acc4 = make_float4(0.f, 0.f, 0.f, 0.f);
#pragma unroll
    for (int j = 0; j < KNN; ++j) {
        const float gj = e[j] * inv;
        const float4 f = *(const float4*)&feats[(size_t)ids[j]*D + l*4];
        acc4.x = fmaf(gj, f.x, acc4.x);
        acc4.y = fmaf(gj, f.y, acc4.y);
        acc4.z = fmaf(gj, f.z, acc4.z);
        acc4.w = fmaf(gj, f.w, acc4.w);
    }
    qv_out = qv;
    fb_out = acc4;
}

// ---------------------------------------------------------------------------
// mega6: r16's mega2 geometry (256 blocks x 512 threads, 8 queries/block)
// with SWIZZLED weight loads: wave wv, n-tile t -> nt = wv*2 + t, k-step ks;
// fragment at ((nt*8+ks)*64 + l)*8 bf16 -> base + l*16B, COALESCED.
// ---------------------------------------------------------------------------
__global__ __launch_bounds__(512) void mega6(const float* __restrict__ qpos,
                                             const float4* __restrict__ bins,
                                             const int* __restrict__ cnt,
                                             const int* __restrict__ spill_cnt,
                                             const float4* __restrict__ spill,
                                             const float* __restrict__ query,
                                             const float* __restrict__ wk2,
                                             const float* __restrict__ w_b,
                                             const float* __restrict__ feats,
                                             const unsigned short* __restrict__ wqs,
                                             const unsigned short* __restrict__ wvs,
                                             const unsigned short* __restrict__ wos,
                                             const float* __restrict__ gmm,
                                             const float* __restrict__ bta,
                                             float* __restrict__ out)
{
    __shared__ unsigned short a_lds[16][264];   // query bf16 (rows 8-15 zero)
    __shared__ unsigned short f_lds[16][264];   // fbar  bf16 (rows 8-15 zero)
    __shared__ unsigned short w_lds[16][264];   // q*v   bf16
    __shared__ float q_f32[8][260];             // query f32 (residual)
    __shared__ float o_f32[8][260];             // out_pre f32 (LN)

    const int tid = threadIdx.x;
    const int wv  = tid >> 6, l = tid & 63;
    const int r0  = blockIdx.x * 8;

    // zero pad rows 8..15 of a_lds / f_lds (512 stores, 1/thread)
    {
        const int arr = tid >> 8;                  // 0: a, 1: f
        const int row = 8 + ((tid >> 5) & 7);
        const int o8  = (tid & 31) * 8;
        const bf16x8 z = {0,0,0,0,0,0,0,0};
        if (arr == 0) *(bf16x8*)&a_lds[row][o8] = z;
        else          *(bf16x8*)&f_lds[row][o8] = z;
    }

    // ---- Phase A: wave wv -> query r0+wv ----
    {
        float4 qv, fb;
        knn_gate_wave(r0 + wv, l, qpos, bins, cnt, spill_cnt, spill,
                      query, wk2, w_b, feats, qv, fb);
        *(float4*)&q_f32[wv][l*4] = qv;
        short4 qb; qb.x = (short)f2b(qv.x); qb.y = (short)f2b(qv.y);
                   qb.z = (short)f2b(qv.z); qb.w = (short)f2b(qv.w);
        *(short4*)&a_lds[wv][l*4] = qb;
        short4 fv; fv.x = (short)f2b(fb.x); fv.y = (short)f2b(fb.y);
                   fv.z = (short)f2b(fb.z); fv.w = (short)f2b(fb.w);
        *(short4*)&f_lds[wv][l*4] = fv;
    }
    __syncthreads();

    // ---- Phase B: MFMA chain, wave wv owns cols [32wv,32wv+32) (2 n-tiles)
    const int mrow = l & 15;
    const int kq   = (l >> 4) * 8;

    f32x4 aq[2], av[2];
#pragma unroll
    for (int t = 0; t < 2; ++t) {
        aq[t] = (f32x4){0.f, 0.f, 0.f, 0.f};
        av[t] = (f32x4){0.f, 0.f, 0.f, 0.f};
    }
#pragma unroll
    for (int ks = 0; ks < 8; ++ks) {
        const bf16x8 af = *(const bf16x8*)&a_lds[mrow][ks*32 + kq];
        const bf16x8 ff = *(const bf16x8*)&f_lds[mrow][ks*32 + kq];
#pragma unroll
        for (int t = 0; t < 2; ++t) {
            const int nt = wv*2 + t;
            const size_t fo = ((size_t)(nt*8 + ks)*64 + l) * 8;
            const bf16x8 bq = *(const bf16x8*)&wqs[fo];
            const bf16x8 bv = *(const bf16x8*)&wvs[fo];
            aq[t] = __builtin_amdgcn_mfma_f32_16x16x32_bf16(af, bq, aq[t], 0, 0, 0);
            av[t] = __builtin_amdgcn_mfma_f32_16x16x32_bf16(ff, bv, av[t], 0, 0, 0);
        }
    }
#pragma unroll
    for (int t = 0; t < 2; ++t) {
#pragma unroll
        for (int r = 0; r < 4; ++r) {
            const int row = (l >> 4) * 4 + r;
            const int col = wv*32 + t*16 + (l & 15);
            w_lds[row][col] = f2b(aq[t][r] * av[t][r]);
        }
    }
    __syncthreads();

    f32x4 ao[2];
#pragma unroll
    for (int t = 0; t < 2; ++t) ao[t] = (f32x4){0.f, 0.f, 0.f, 0.f};
#pragma unroll
    for (int ks = 0; ks < 8; ++ks) {
        const bf16x8 wf = *(const bf16x8*)&w_lds[mrow][ks*32 + kq];
#pragma unroll
        for (int t = 0; t < 2; ++t) {
            const int nt = wv*2 + t;
            const size_t fo = ((size_t)(nt*8 + ks)*64 + l) * 8;
            const bf16x8 bo = *(const bf16x8*)&wos[fo];
            ao[t] = __builtin_amdgcn_mfma_f32_16x16x32_bf16(wf, bo, ao[t], 0, 0, 0);
        }
    }
#pragma unroll
    for (int t = 0; t < 2; ++t) {
#pragma unroll
        for (int r = 0; r < 4; ++r) {
            const int row = (l >> 4) * 4 + r;
            if (row < 8) {
                const int col = wv*32 + t*16 + (l & 15);
                o_f32[row][col] = ao[t][r] + q_f32[row][col];
            }
        }
    }
    __syncthreads();

    // ---- LayerNorm: wave wv -> row wv ----
    {
        const float4 v = *(const float4*)&o_f32[wv][l*4];
        float s  = (v.x + v.y) + (v.z + v.w);
        float s2 = fmaf(v.x, v.x, fmaf(v.y, v.y, fmaf(v.z, v.z, v.w*v.w)));
#pragma unroll
        for (int o = 32; o; o >>= 1) { s += __shfl_xor(s, o); s2 += __shfl_xor(s2, o); }
        const float mu  = s * (1.f/256.f);
        const float var = fmaf(s2, 1.f/256.f, -mu*mu);
        const float rs  = rsqrtf(var + 1e-5f);
        const float4 g = *(const float4*)&gmm[l*4];
        const float4 b = *(const float4*)&bta[l*4];
        float4 o4;
        o4.x = (v.x - mu) * rs * g.x + b.x;
        o4.y = (v.y - mu) * rs * g.y + b.y;
        o4.z = (v.z - mu) * rs * g.z + b.z;
        o4.w = (v.w - mu) * rs * g.w + b.w;
        *(float4*)&out[(size_t)(r0+wv)*D + l*4] = o4;
    }
}

// ---------------------------------------------------------------------------
extern "C" void kernel_launch(void* const* d_in, const int* in_sizes, int n_in,
                              void* d_out, int out_size, void* d_ws, size_t ws_size,
                              hipStream_t stream)
{
    const float* query = (const float*)d_in[0];
    const float* qpos  = (const float*)d_in[1];
    const float* feats = (const float*)d_in[2];
    const float* spc   = (const float*)d_in[3];
    const float* w_q   = (const float*)d_in[4];
    const float* w_v   = (const float*)d_in[5];
    const float* w_o   = (const float*)d_in[6];
    const float* w_k   = (const float*)d_in[7];
    const float* w_b   = (const float*)d_in[8];
    const float* gamma = (const float*)d_in[9];
    const float* beta  = (const float*)d_in[10];

    const int Nq = in_sizes[0] / D;   // 2048
    const int N  = in_sizes[2] / D;   // 50000

    char* ws = (char*)d_ws;
    size_t off = 0;
    int* cnt = (int*)(ws + off);               off += ((size_t)NCELL * 4 + 255) & ~(size_t)255;
    int* spill_cnt = (int*)(ws + off);         off += 256;
    float* wk2 = (float*)(ws + off);           off += ((size_t)KNN * D * 4 + 255) & ~(size_t)255;
    unsigned short* wqs = (unsigned short*)(ws + off); off += (size_t)D * D * 2;
    unsigned short* wvs = (unsigned short*)(ws + off); off += (size_t)D * D * 2;
    unsigned short* wos = (unsigned short*)(ws + off); off += (size_t)D * D * 2;
    float4* bins = (float4*)(ws + off);        off += ((size_t)NCELL * CAP * 16 + 255) & ~(size_t)255;
    float4* spill = (float4*)(ws + off);       off += ((size_t)SPILLMAX * 16 + 255) & ~(size_t)255;

    prep<<<108, 256, 0, stream>>>(w_k, w_q, w_v, w_o, wk2, wqs, wvs, wos,
                                  (int4*)cnt, spill_cnt);
    scatter_bins<<<(N + 255)/256, 256, 0, stream>>>(spc, cnt, bins, spill_cnt, spill, N);
    mega6<<<Nq/8, 512, 0, stream>>>(qpos, bins, cnt, spill_cnt, spill,
                                    query, wk2, w_b, feats, wqs, wvs, wos,
                                    gamma, beta, (float*)d_out);
}